// Round 1
// baseline (265.936 us; speedup 1.0000x reference)
//
#include <hip/hip_runtime.h>
#include <math.h>

// Problem constants from setup_inputs(): B=8, N=4096, C=768, H=W=64 (patch_h/w=64), GROUPS=4.
#define BB 8
#define CC 768
#define HH 64
#define WW 64
#define NN (HH * WW)
#define GG 4
#define CG (CC / GG) /* 192 */

// ---------------------------------------------------------------------------
// Kernel A: per spatial position (b, h, w), compute the 8 offset values
// (depthwise 3x3 conv + GELU, dot with off_w; center pixel dot with wt_w,
// sigmoid gate; add group shifts) and store clipped sample coords ix, iy
// per (b, g, hw) into workspace.
// One wave (64 lanes) per position; each lane covers 12 channels.
// ---------------------------------------------------------------------------
__global__ __launch_bounds__(256) void dqshift_offsets_kernel(
    const float* __restrict__ x,     // (B, N, C)
    const float* __restrict__ dw_w,  // (C, 1, 3, 3) -> (C, 9)
    const float* __restrict__ dw_b,  // (C,)
    const float* __restrict__ off_w, // (8, C)
    const float* __restrict__ off_b, // (8,)
    const float* __restrict__ wt_w,  // (8, C)
    const float* __restrict__ wt_b,  // (8,)
    float* __restrict__ ixiy)        // (2, B*G, N): ix plane then iy plane
{
    const int wave = threadIdx.x >> 6;
    const int lane = threadIdx.x & 63;
    const int p    = blockIdx.x * 4 + wave;   // position over B*N (grid exact)
    const int b    = p >> 12;                 // / 4096
    const int hw   = p & 4095;
    const int h    = hw >> 6;
    const int w    = hw & 63;

    const float* xb = x + (size_t)b * NN * CC;

    float accO[8], accW[8];
#pragma unroll
    for (int o = 0; o < 8; ++o) { accO[o] = 0.f; accW[o] = 0.f; }

    for (int k = 0; k < CC / 64; ++k) {
        const int c = lane + (k << 6);
        // depthwise 3x3 conv, zero padding
        float conv = 0.f;
        float xc = 0.f;
#pragma unroll
        for (int dy = -1; dy <= 1; ++dy) {
            const int hh = h + dy;
            const bool vy = (hh >= 0) && (hh < HH);
#pragma unroll
            for (int dx = -1; dx <= 1; ++dx) {
                const int ww = w + dx;
                const bool v = vy && (ww >= 0) && (ww < WW);
                const float t = v ? xb[(size_t)(hh * WW + ww) * CC + c] : 0.f;
                if (dy == 0 && dx == 0) xc = t;  // center pixel reused for wt
                const float wgt = dw_w[c * 9 + (dy + 1) * 3 + (dx + 1)];
                conv = fmaf(t, wgt, conv);
            }
        }
        const float gv = conv + dw_b[c];
        // exact GELU: 0.5*v*(1+erf(v/sqrt(2)))
        const float gl = 0.5f * gv * (1.0f + erff(gv * 0.70710678118654752f));
#pragma unroll
        for (int o = 0; o < 8; ++o) {
            accO[o] = fmaf(gl, off_w[o * CC + c], accO[o]);
            accW[o] = fmaf(xc, wt_w[o * CC + c], accW[o]);
        }
    }

    // wave64 butterfly reduction of the 16 accumulators
#pragma unroll
    for (int o = 0; o < 8; ++o) {
#pragma unroll
        for (int s = 32; s > 0; s >>= 1) {
            accO[o] += __shfl_xor(accO[o], s, 64);
            accW[o] += __shfl_xor(accW[o], s, 64);
        }
    }

    if (lane == 0) {
        const float shx[4] = {0.f, 0.f, -1.f, 1.f};
        const float shy[4] = {-1.f, 1.f, 0.f, 0.f};
#pragma unroll
        for (int g = 0; g < 4; ++g) {
            const float sx = 1.f / (1.f + expf(-(accW[g] + wt_b[g])));
            const float sy = 1.f / (1.f + expf(-(accW[4 + g] + wt_b[4 + g])));
            const float ox = (accO[g] + off_b[g]) * sx + shx[g];
            const float oy = (accO[4 + g] + off_b[4 + g]) * sy + shy[g];
            // grid_sample transform collapses to: ix = clip(w+ox), iy = clip(h+oy)
            const float ix = fminf(fmaxf((float)w + ox, 0.f), (float)(WW - 1));
            const float iy = fminf(fmaxf((float)h + oy, 0.f), (float)(HH - 1));
            const int idx = (b * GG + g) * NN + hw;
            ixiy[idx] = ix;
            ixiy[BB * GG * NN + idx] = iy;
        }
    }
}

// ---------------------------------------------------------------------------
// Kernel B: bilinear border sampling. One block per (b, hw) position;
// thread t covers channels t, t+256, t+512. Output (B, N, C) contiguous.
// ---------------------------------------------------------------------------
__global__ __launch_bounds__(256) void dqshift_sample_kernel(
    const float* __restrict__ x,     // (B, N, C)
    const float* __restrict__ ixiy,  // (2, B*G, N)
    float* __restrict__ out)         // (B, N, C)
{
    const int p  = blockIdx.x;       // over B*N
    const int b  = p >> 12;
    const int hw = p & 4095;

    const float* xb = x + (size_t)b * NN * CC;
    float* ob = out + (size_t)p * CC;

#pragma unroll
    for (int k = 0; k < 3; ++k) {
        const int c = threadIdx.x + (k << 8);
        const int g = c / CG;
        const int idx = (b * GG + g) * NN + hw;
        const float ix = ixiy[idx];
        const float iy = ixiy[BB * GG * NN + idx];

        const float x0f = floorf(ix);
        const float y0f = floorf(iy);
        const float wx = ix - x0f;
        const float wy = iy - y0f;
        const int x0 = (int)x0f;
        const int y0 = (int)y0f;
        const int x1 = min(x0 + 1, WW - 1);
        const int y1 = min(y0 + 1, HH - 1);

        const float* r0 = xb + (size_t)(y0 * WW) * CC + c;
        const float* r1 = xb + (size_t)(y1 * WW) * CC + c;
        const float v00 = r0[(size_t)x0 * CC];
        const float v01 = r0[(size_t)x1 * CC];
        const float v10 = r1[(size_t)x0 * CC];
        const float v11 = r1[(size_t)x1 * CC];

        ob[c] = v00 * (1.f - wx) * (1.f - wy) + v01 * wx * (1.f - wy)
              + v10 * (1.f - wx) * wy + v11 * wx * wy;
    }
}

extern "C" void kernel_launch(void* const* d_in, const int* in_sizes, int n_in,
                              void* d_out, int out_size, void* d_ws, size_t ws_size,
                              hipStream_t stream) {
    const float* x     = (const float*)d_in[0];
    const float* dw_w  = (const float*)d_in[1];
    const float* dw_b  = (const float*)d_in[2];
    const float* off_w = (const float*)d_in[3];
    const float* off_b = (const float*)d_in[4];
    const float* wt_w  = (const float*)d_in[5];
    const float* wt_b  = (const float*)d_in[6];
    // d_in[7] = offset_list (unused by reference), d_in[8]/d_in[9] = patch_h/patch_w (=64, hardcoded)

    float* ixiy = (float*)d_ws;          // needs 2*B*G*N*4 = 1 MiB
    float* out  = (float*)d_out;

    // Kernel A: one wave per position, 4 waves per block
    dqshift_offsets_kernel<<<BB * NN / 4, 256, 0, stream>>>(
        x, dw_w, dw_b, off_w, off_b, wt_w, wt_b, ixiy);

    // Kernel B: one block per position
    dqshift_sample_kernel<<<BB * NN, 256, 0, stream>>>(x, ixiy, out);
}

// Round 2
// 211.443 us; speedup vs baseline: 1.2577x; 1.2577x over previous
//
#include <hip/hip_runtime.h>
#include <math.h>

// Problem constants: B=8, N=4096, C=768, H=W=64, GROUPS=4.
#define BB 8
#define CC 768
#define HH 64
#define WW 64
#define NN 4096
#define GG 4
#define NCHUNK 6
#define CHUNK 128   /* channels per A1 block */

__device__ __forceinline__ float gelu_exact(float v) {
    return 0.5f * v * (1.0f + erff(v * 0.70710678118654752f));
}

// ---------------------------------------------------------------------------
// A1: block = (b, h, channel-chunk of 128). Thread = one channel.
// Sliding-window 3x3 depthwise conv along w (each x value loaded <=3x),
// exact GELU, stage gl[c][w] in LDS; phase 2: off-einsum partial sums for the
// chunk (off_w addresses wave-uniform -> scalar loads), write 8 partials per
// (chunk, position) to workspace.
// ---------------------------------------------------------------------------
__global__ __launch_bounds__(128) void dq_conv_offpart(
    const float* __restrict__ x,      // (B, N, C)
    const float* __restrict__ dw_w,   // (C, 9)
    const float* __restrict__ dw_b,   // (C,)
    const float* __restrict__ off_w,  // (8, C)
    float* __restrict__ offpart)      // (B*N, 48): [pos][chunk*8 + o]
{
    __shared__ float gl[CHUNK][WW + 1];   // 33 KB, conflict-free both phases
    const int t = threadIdx.x;
    int bid = blockIdx.x;
    const int chunk = bid % NCHUNK; bid /= NCHUNK;
    const int h = bid % HH;
    const int b = bid / HH;
    const int c = chunk * CHUNK + t;

    float w9[9];
#pragma unroll
    for (int j = 0; j < 9; ++j) w9[j] = dw_w[c * 9 + j];
    const float bias = dw_b[c];

    const float* rowc = x + (size_t)(b * NN + h * WW) * CC + c;  // (h, w=0, c)
    const bool hm = (h > 0), hp = (h < HH - 1);
    const int RS = WW * CC;  // row stride in floats

    // window columns: L (w-1), C (w), R (w+1); rows h-1, h, h+1
    float L0 = 0.f, L1 = 0.f, L2 = 0.f;
    float C0, C1, C2, R0, R1, R2;
    C0 = hm ? rowc[-RS] : 0.f;
    C1 = rowc[0];
    C2 = hp ? rowc[RS] : 0.f;

#pragma unroll 4
    for (int w = 0; w < WW; ++w) {
        if (w < WW - 1) {
            const int o = (w + 1) * CC;
            R0 = hm ? rowc[o - RS] : 0.f;
            R1 = rowc[o];
            R2 = hp ? rowc[o + RS] : 0.f;
        } else { R0 = 0.f; R1 = 0.f; R2 = 0.f; }
        float conv = L0 * w9[0] + C0 * w9[1] + R0 * w9[2]
                   + L1 * w9[3] + C1 * w9[4] + R1 * w9[5]
                   + L2 * w9[6] + C2 * w9[7] + R2 * w9[8];
        gl[t][w] = gelu_exact(conv + bias);
        L0 = C0; L1 = C1; L2 = C2;
        C0 = R0; C1 = R1; C2 = R2;
    }
    __syncthreads();

    // phase 2: off partial sums. thread (p = t&63, og = t>>6) does outputs og*4..og*4+3
    const int p = t & 63, og = t >> 6;
    float a0 = 0.f, a1 = 0.f, a2 = 0.f, a3 = 0.f;
    const float* wo = off_w + (og * 4) * CC + chunk * CHUNK;  // wave-uniform
#pragma unroll 16
    for (int cl = 0; cl < CHUNK; ++cl) {
        const float g = gl[cl][p];
        a0 = fmaf(g, wo[cl], a0);
        a1 = fmaf(g, wo[CC + cl], a1);
        a2 = fmaf(g, wo[2 * CC + cl], a2);
        a3 = fmaf(g, wo[3 * CC + cl], a3);
    }
    const int pos = (b * HH + h) * WW + p;
    float4 v; v.x = a0; v.y = a1; v.z = a2; v.w = a3;
    *(float4*)(offpart + (size_t)pos * 48 + chunk * 8 + og * 4) = v;
}

// ---------------------------------------------------------------------------
// A2: one wave per position. wt einsum (coalesced float4, butterfly reduce),
// combine the 6 chunk off-partials, sigmoid gate + shifts, clipped coords.
// ---------------------------------------------------------------------------
__global__ __launch_bounds__(256) void dq_coords(
    const float* __restrict__ x,
    const float* __restrict__ offpart,
    const float* __restrict__ off_b,
    const float* __restrict__ wt_w,
    const float* __restrict__ wt_b,
    float* __restrict__ ixiy)        // (2, B*G, N)
{
    const int lane = threadIdx.x & 63;
    const int pos = blockIdx.x * 4 + (threadIdx.x >> 6);
    const int b = pos >> 12;
    const int hw = pos & 4095;
    const int h = hw >> 6, w = hw & 63;

    // wt dot over C, lanes cover 4 channels each per iteration
    float acc[8];
#pragma unroll
    for (int o = 0; o < 8; ++o) acc[o] = 0.f;
    const float* xp = x + (size_t)pos * CC;
#pragma unroll
    for (int k = 0; k < 3; ++k) {
        const int c0 = (k * 64 + lane) * 4;
        const float4 xv = *(const float4*)(xp + c0);
#pragma unroll
        for (int o = 0; o < 8; ++o) {
            const float4 wv = *(const float4*)(wt_w + o * CC + c0);
            acc[o] = fmaf(xv.x, wv.x, fmaf(xv.y, wv.y, fmaf(xv.z, wv.z, fmaf(xv.w, wv.w, acc[o]))));
        }
    }
#pragma unroll
    for (int o = 0; o < 8; ++o) {
#pragma unroll
        for (int s = 32; s; s >>= 1) acc[o] += __shfl_xor(acc[o], s, 64);
    }

    // off partials: lane l < 48 holds offpart[pos][l], l = chunk*8 + o
    float v = (lane < 48) ? offpart[(size_t)pos * 48 + lane] : 0.f;
    float s = v;
#pragma unroll
    for (int j = 1; j < 6; ++j) s += __shfl(v, lane + 8 * j, 64);
    // lanes 0..7: s = total off dot for output o = lane

    // select acc[lane] (wt sum for o = lane)
    float wts = acc[0];
#pragma unroll
    for (int o = 1; o < 8; ++o) wts = (lane == o) ? acc[o] : wts;

    if (lane < 8) {
        const float sig = 1.f / (1.f + expf(-(wts + wt_b[lane])));
        const float val = (s + off_b[lane]) * sig;
        if (lane < 4) {
            const float shx = (lane == 2) ? -1.f : ((lane == 3) ? 1.f : 0.f);
            const float ix = fminf(fmaxf((float)w + val + shx, 0.f), (float)(WW - 1));
            ixiy[(b * GG + lane) * NN + hw] = ix;
        } else {
            const int g = lane - 4;
            const float shy = (g == 0) ? -1.f : ((g == 1) ? 1.f : 0.f);
            const float iy = fminf(fmaxf((float)h + val + shy, 0.f), (float)(HH - 1));
            ixiy[BB * GG * NN + (b * GG + g) * NN + hw] = iy;
        }
    }
}

// ---------------------------------------------------------------------------
// Fallback kernel (round-1 fused version) if ws_size is too small for partials.
// ---------------------------------------------------------------------------
__global__ __launch_bounds__(256) void dqshift_offsets_kernel(
    const float* __restrict__ x, const float* __restrict__ dw_w,
    const float* __restrict__ dw_b, const float* __restrict__ off_w,
    const float* __restrict__ off_b, const float* __restrict__ wt_w,
    const float* __restrict__ wt_b, float* __restrict__ ixiy)
{
    const int wave = threadIdx.x >> 6;
    const int lane = threadIdx.x & 63;
    const int p = blockIdx.x * 4 + wave;
    const int b = p >> 12;
    const int hw = p & 4095;
    const int h = hw >> 6;
    const int w = hw & 63;
    const float* xb = x + (size_t)b * NN * CC;
    float accO[8], accW[8];
#pragma unroll
    for (int o = 0; o < 8; ++o) { accO[o] = 0.f; accW[o] = 0.f; }
    for (int k = 0; k < CC / 64; ++k) {
        const int c = lane + (k << 6);
        float conv = 0.f, xc = 0.f;
#pragma unroll
        for (int dy = -1; dy <= 1; ++dy) {
            const int hh = h + dy;
            const bool vy = (hh >= 0) && (hh < HH);
#pragma unroll
            for (int dx = -1; dx <= 1; ++dx) {
                const int ww = w + dx;
                const bool vv = vy && (ww >= 0) && (ww < WW);
                const float tt = vv ? xb[(size_t)(hh * WW + ww) * CC + c] : 0.f;
                if (dy == 0 && dx == 0) xc = tt;
                conv = fmaf(tt, dw_w[c * 9 + (dy + 1) * 3 + (dx + 1)], conv);
            }
        }
        const float gv = conv + dw_b[c];
        const float gle = 0.5f * gv * (1.0f + erff(gv * 0.70710678118654752f));
#pragma unroll
        for (int o = 0; o < 8; ++o) {
            accO[o] = fmaf(gle, off_w[o * CC + c], accO[o]);
            accW[o] = fmaf(xc, wt_w[o * CC + c], accW[o]);
        }
    }
#pragma unroll
    for (int o = 0; o < 8; ++o) {
#pragma unroll
        for (int s = 32; s > 0; s >>= 1) {
            accO[o] += __shfl_xor(accO[o], s, 64);
            accW[o] += __shfl_xor(accW[o], s, 64);
        }
    }
    if (lane == 0) {
        const float shx[4] = {0.f, 0.f, -1.f, 1.f};
        const float shy[4] = {-1.f, 1.f, 0.f, 0.f};
#pragma unroll
        for (int g = 0; g < 4; ++g) {
            const float sx = 1.f / (1.f + expf(-(accW[g] + wt_b[g])));
            const float sy = 1.f / (1.f + expf(-(accW[4 + g] + wt_b[4 + g])));
            const float ox = (accO[g] + off_b[g]) * sx + shx[g];
            const float oy = (accO[4 + g] + off_b[4 + g]) * sy + shy[g];
            const float ix = fminf(fmaxf((float)w + ox, 0.f), (float)(WW - 1));
            const float iy = fminf(fmaxf((float)h + oy, 0.f), (float)(HH - 1));
            const int idx = (b * GG + g) * NN + hw;
            ixiy[idx] = ix;
            ixiy[BB * GG * NN + idx] = iy;
        }
    }
}

// ---------------------------------------------------------------------------
// B: bilinear border sampling, one block per position, channel-coalesced.
// ---------------------------------------------------------------------------
__global__ __launch_bounds__(256) void dqshift_sample_kernel(
    const float* __restrict__ x,
    const float* __restrict__ ixiy,
    float* __restrict__ out)
{
    const int p = blockIdx.x;
    const int b = p >> 12;
    const int hw = p & 4095;
    const float* xb = x + (size_t)b * NN * CC;
    float* ob = out + (size_t)p * CC;

#pragma unroll
    for (int k = 0; k < 3; ++k) {
        const int c = threadIdx.x + (k << 8);
        const int g = c / (CC / GG);
        const int idx = (b * GG + g) * NN + hw;
        const float ix = ixiy[idx];
        const float iy = ixiy[BB * GG * NN + idx];
        const float x0f = floorf(ix);
        const float y0f = floorf(iy);
        const float wx = ix - x0f;
        const float wy = iy - y0f;
        const int x0 = (int)x0f;
        const int y0 = (int)y0f;
        const int x1 = min(x0 + 1, WW - 1);
        const int y1 = min(y0 + 1, HH - 1);
        const float* r0 = xb + (size_t)(y0 * WW) * CC + c;
        const float* r1 = xb + (size_t)(y1 * WW) * CC + c;
        const float v00 = r0[(size_t)x0 * CC];
        const float v01 = r0[(size_t)x1 * CC];
        const float v10 = r1[(size_t)x0 * CC];
        const float v11 = r1[(size_t)x1 * CC];
        ob[c] = v00 * (1.f - wx) * (1.f - wy) + v01 * wx * (1.f - wy)
              + v10 * (1.f - wx) * wy + v11 * wx * wy;
    }
}

extern "C" void kernel_launch(void* const* d_in, const int* in_sizes, int n_in,
                              void* d_out, int out_size, void* d_ws, size_t ws_size,
                              hipStream_t stream) {
    const float* x     = (const float*)d_in[0];
    const float* dw_w  = (const float*)d_in[1];
    const float* dw_b  = (const float*)d_in[2];
    const float* off_w = (const float*)d_in[3];
    const float* off_b = (const float*)d_in[4];
    const float* wt_w  = (const float*)d_in[5];
    const float* wt_b  = (const float*)d_in[6];

    float* ixiy = (float*)d_ws;                             // 1 MiB
    float* offpart = (float*)d_ws + 2 * BB * GG * NN;       // 6.29 MiB
    const size_t need = (size_t)(2 * BB * GG * NN + BB * NN * 48) * 4;

    if (ws_size >= need) {
        dq_conv_offpart<<<BB * HH * NCHUNK, CHUNK, 0, stream>>>(
            x, dw_w, dw_b, off_w, offpart);
        dq_coords<<<BB * NN / 4, 256, 0, stream>>>(
            x, offpart, off_b, wt_w, wt_b, ixiy);
    } else {
        dqshift_offsets_kernel<<<BB * NN / 4, 256, 0, stream>>>(
            x, dw_w, dw_b, off_w, off_b, wt_w, wt_b, ixiy);
    }
    dqshift_sample_kernel<<<BB * NN, 256, 0, stream>>>(x, ixiy, d_out ? (float*)d_out : nullptr);
}

// Round 3
// 147.669 us; speedup vs baseline: 1.8009x; 1.4319x over previous
//
#include <hip/hip_runtime.h>
#include <math.h>

// Problem constants: B=8, N=4096, C=768, H=W=64, GROUPS=4.
#define BB 8
#define CC 768
#define HH 64
#define WW 64
#define NN 4096
#define GG 4
#define NCHUNK 6
#define CHUNK 128   /* channels per A1 block */

__device__ __forceinline__ float gelu_exact(float v) {
    return 0.5f * v * (1.0f + erff(v * 0.70710678118654752f));
}

typedef __attribute__((ext_vector_type(8))) _Float16 half8;

// ---------------------------------------------------------------------------
// A1: block = (b, h, channel-chunk of 128). Thread = one channel.
// Phase 1: depthwise 3x3 conv along the row, batched 8 columns at a time with
// register prefetch of the next batch (24 independent loads in flight);
// exact GELU -> fp16 -> LDS glT[w][c] (272 B row stride: 16B-aligned, b128
// reads are bank-packed). Phase 2: off-einsum partials; og = wave index so
// off_w addresses are wave-uniform (s_load); ds_read_b128 pulls 8 gelus/inst.
// ---------------------------------------------------------------------------
__global__ __launch_bounds__(128, 5) void dq_conv_offpart(
    const float* __restrict__ x,      // (B, N, C)
    const float* __restrict__ dw_w,   // (C, 9)
    const float* __restrict__ dw_b,   // (C,)
    const float* __restrict__ off_w,  // (8, C)
    float* __restrict__ offpart)      // (B*N, 48): [pos][chunk*8 + o]
{
    __shared__ _Float16 glT[WW][136];   // 17.4 KB -> 9 blocks/CU
    const int t = threadIdx.x;
    int bid = blockIdx.x;
    const int chunk = bid % NCHUNK; bid /= NCHUNK;
    const int h = bid % HH;
    const int b = bid / HH;
    const int c = chunk * CHUNK + t;

    float w9[9];
#pragma unroll
    for (int j = 0; j < 9; ++j) w9[j] = dw_w[c * 9 + j];
    const float bias = dw_b[c];

    const float* rowc = x + (size_t)(b * NN + h * WW) * CC + c;  // (h, w=0, c)
    const bool hm = (h > 0), hp = (h < HH - 1);
    const int RS = WW * CC;

    float cur0[8], cur1[8], cur2[8], nxt0[8], nxt1[8], nxt2[8];
    float pl0 = 0.f, pl1 = 0.f, pl2 = 0.f;   // column w-1 carry

#pragma unroll
    for (int j = 0; j < 8; ++j) {
        const float* p = rowc + (size_t)j * CC;
        cur1[j] = p[0];
        cur0[j] = hm ? p[-RS] : 0.f;
        cur2[j] = hp ? p[RS] : 0.f;
    }

    for (int wb = 0; wb < 8; ++wb) {
        if (wb < 7) {
#pragma unroll
            for (int j = 0; j < 8; ++j) {
                const float* p = rowc + (size_t)(wb * 8 + 8 + j) * CC;
                nxt1[j] = p[0];
                nxt0[j] = hm ? p[-RS] : 0.f;
                nxt2[j] = hp ? p[RS] : 0.f;
            }
        } else {
#pragma unroll
            for (int j = 0; j < 8; ++j) { nxt0[j] = 0.f; nxt1[j] = 0.f; nxt2[j] = 0.f; }
        }
#pragma unroll
        for (int j = 0; j < 8; ++j) {
            const float l0 = j ? cur0[j - 1] : pl0;
            const float l1 = j ? cur1[j - 1] : pl1;
            const float l2 = j ? cur2[j - 1] : pl2;
            const float r0 = (j == 7) ? nxt0[0] : cur0[j + 1];
            const float r1 = (j == 7) ? nxt1[0] : cur1[j + 1];
            const float r2 = (j == 7) ? nxt2[0] : cur2[j + 1];
            float conv = l0 * w9[0] + cur0[j] * w9[1] + r0 * w9[2]
                       + l1 * w9[3] + cur1[j] * w9[4] + r1 * w9[5]
                       + l2 * w9[6] + cur2[j] * w9[7] + r2 * w9[8];
            glT[wb * 8 + j][t] = (_Float16)gelu_exact(conv + bias);
        }
        pl0 = cur0[7]; pl1 = cur1[7]; pl2 = cur2[7];
#pragma unroll
        for (int j = 0; j < 8; ++j) { cur0[j] = nxt0[j]; cur1[j] = nxt1[j]; cur2[j] = nxt2[j]; }
    }
    __syncthreads();

    // phase 2: lane p = position, wave og -> outputs og*4..og*4+3 (wave-uniform)
    const int p = t & 63, og = t >> 6;
    float a0 = 0.f, a1 = 0.f, a2 = 0.f, a3 = 0.f;
    const float* wo = off_w + (og * 4) * CC + chunk * CHUNK;
    const half8* rowp = (const half8*)&glT[p][0];   // 272-B row: 16B aligned
#pragma unroll
    for (int k = 0; k < 16; ++k) {
        const half8 hv = rowp[k];
        float g[8];
#pragma unroll
        for (int j = 0; j < 8; ++j) g[j] = (float)hv[j];
#pragma unroll
        for (int j = 0; j < 8; ++j) {
            const int cl = k * 8 + j;
            a0 = fmaf(g[j], wo[cl], a0);
            a1 = fmaf(g[j], wo[CC + cl], a1);
            a2 = fmaf(g[j], wo[2 * CC + cl], a2);
            a3 = fmaf(g[j], wo[3 * CC + cl], a3);
        }
    }
    const int pos = (b * HH + h) * WW + p;
    float4 v; v.x = a0; v.y = a1; v.z = a2; v.w = a3;
    *(float4*)(offpart + (size_t)pos * 48 + chunk * 8 + og * 4) = v;
}

// ---------------------------------------------------------------------------
// A2: one wave per position. wt einsum (coalesced float4, butterfly reduce),
// combine the 6 chunk off-partials, sigmoid gate + shifts, clipped coords.
// ---------------------------------------------------------------------------
__global__ __launch_bounds__(256) void dq_coords(
    const float* __restrict__ x,
    const float* __restrict__ offpart,
    const float* __restrict__ off_b,
    const float* __restrict__ wt_w,
    const float* __restrict__ wt_b,
    float* __restrict__ ixiy)        // (2, B*G, N)
{
    const int lane = threadIdx.x & 63;
    const int pos = blockIdx.x * 4 + (threadIdx.x >> 6);
    const int b = pos >> 12;
    const int hw = pos & 4095;
    const int h = hw >> 6, w = hw & 63;

    float acc[8];
#pragma unroll
    for (int o = 0; o < 8; ++o) acc[o] = 0.f;
    const float* xp = x + (size_t)pos * CC;
#pragma unroll
    for (int k = 0; k < 3; ++k) {
        const int c0 = (k * 64 + lane) * 4;
        const float4 xv = *(const float4*)(xp + c0);
#pragma unroll
        for (int o = 0; o < 8; ++o) {
            const float4 wv = *(const float4*)(wt_w + o * CC + c0);
            acc[o] = fmaf(xv.x, wv.x, fmaf(xv.y, wv.y, fmaf(xv.z, wv.z, fmaf(xv.w, wv.w, acc[o]))));
        }
    }
#pragma unroll
    for (int o = 0; o < 8; ++o) {
#pragma unroll
        for (int s = 32; s; s >>= 1) acc[o] += __shfl_xor(acc[o], s, 64);
    }

    float v = (lane < 48) ? offpart[(size_t)pos * 48 + lane] : 0.f;
    float s = v;
#pragma unroll
    for (int j = 1; j < 6; ++j) s += __shfl(v, lane + 8 * j, 64);

    float wts = acc[0];
#pragma unroll
    for (int o = 1; o < 8; ++o) wts = (lane == o) ? acc[o] : wts;

    if (lane < 8) {
        const float sig = 1.f / (1.f + expf(-(wts + wt_b[lane])));
        const float val = (s + off_b[lane]) * sig;
        if (lane < 4) {
            const float shx = (lane == 2) ? -1.f : ((lane == 3) ? 1.f : 0.f);
            const float ix = fminf(fmaxf((float)w + val + shx, 0.f), (float)(WW - 1));
            ixiy[(b * GG + lane) * NN + hw] = ix;
        } else {
            const int g = lane - 4;
            const float shy = (g == 0) ? -1.f : ((g == 1) ? 1.f : 0.f);
            const float iy = fminf(fmaxf((float)h + val + shy, 0.f), (float)(HH - 1));
            ixiy[BB * GG * NN + (b * GG + g) * NN + hw] = iy;
        }
    }
}

// ---------------------------------------------------------------------------
// Fallback kernel (round-1 fused version) if ws_size is too small for partials.
// ---------------------------------------------------------------------------
__global__ __launch_bounds__(256) void dqshift_offsets_kernel(
    const float* __restrict__ x, const float* __restrict__ dw_w,
    const float* __restrict__ dw_b, const float* __restrict__ off_w,
    const float* __restrict__ off_b, const float* __restrict__ wt_w,
    const float* __restrict__ wt_b, float* __restrict__ ixiy)
{
    const int wave = threadIdx.x >> 6;
    const int lane = threadIdx.x & 63;
    const int p = blockIdx.x * 4 + wave;
    const int b = p >> 12;
    const int hw = p & 4095;
    const int h = hw >> 6;
    const int w = hw & 63;
    const float* xb = x + (size_t)b * NN * CC;
    float accO[8], accW[8];
#pragma unroll
    for (int o = 0; o < 8; ++o) { accO[o] = 0.f; accW[o] = 0.f; }
    for (int k = 0; k < CC / 64; ++k) {
        const int c = lane + (k << 6);
        float conv = 0.f, xc = 0.f;
#pragma unroll
        for (int dy = -1; dy <= 1; ++dy) {
            const int hh = h + dy;
            const bool vy = (hh >= 0) && (hh < HH);
#pragma unroll
            for (int dx = -1; dx <= 1; ++dx) {
                const int ww = w + dx;
                const bool vv = vy && (ww >= 0) && (ww < WW);
                const float tt = vv ? xb[(size_t)(hh * WW + ww) * CC + c] : 0.f;
                if (dy == 0 && dx == 0) xc = tt;
                conv = fmaf(tt, dw_w[c * 9 + (dy + 1) * 3 + (dx + 1)], conv);
            }
        }
        const float gv = conv + dw_b[c];
        const float gle = 0.5f * gv * (1.0f + erff(gv * 0.70710678118654752f));
#pragma unroll
        for (int o = 0; o < 8; ++o) {
            accO[o] = fmaf(gle, off_w[o * CC + c], accO[o]);
            accW[o] = fmaf(xc, wt_w[o * CC + c], accW[o]);
        }
    }
#pragma unroll
    for (int o = 0; o < 8; ++o) {
#pragma unroll
        for (int s = 32; s > 0; s >>= 1) {
            accO[o] += __shfl_xor(accO[o], s, 64);
            accW[o] += __shfl_xor(accW[o], s, 64);
        }
    }
    if (lane == 0) {
        const float shx[4] = {0.f, 0.f, -1.f, 1.f};
        const float shy[4] = {-1.f, 1.f, 0.f, 0.f};
#pragma unroll
        for (int g = 0; g < 4; ++g) {
            const float sx = 1.f / (1.f + expf(-(accW[g] + wt_b[g])));
            const float sy = 1.f / (1.f + expf(-(accW[4 + g] + wt_b[4 + g])));
            const float ox = (accO[g] + off_b[g]) * sx + shx[g];
            const float oy = (accO[4 + g] + off_b[4 + g]) * sy + shy[g];
            const float ix = fminf(fmaxf((float)w + ox, 0.f), (float)(WW - 1));
            const float iy = fminf(fmaxf((float)h + oy, 0.f), (float)(HH - 1));
            const int idx = (b * GG + g) * NN + hw;
            ixiy[idx] = ix;
            ixiy[BB * GG * NN + idx] = iy;
        }
    }
}

// ---------------------------------------------------------------------------
// B: bilinear border sampling, one block per position, channel-coalesced.
// ---------------------------------------------------------------------------
__global__ __launch_bounds__(256) void dqshift_sample_kernel(
    const float* __restrict__ x,
    const float* __restrict__ ixiy,
    float* __restrict__ out)
{
    const int p = blockIdx.x;
    const int b = p >> 12;
    const int hw = p & 4095;
    const float* xb = x + (size_t)b * NN * CC;
    float* ob = out + (size_t)p * CC;

#pragma unroll
    for (int k = 0; k < 3; ++k) {
        const int c = threadIdx.x + (k << 8);
        const int g = c / (CC / GG);
        const int idx = (b * GG + g) * NN + hw;
        const float ix = ixiy[idx];
        const float iy = ixiy[BB * GG * NN + idx];
        const float x0f = floorf(ix);
        const float y0f = floorf(iy);
        const float wx = ix - x0f;
        const float wy = iy - y0f;
        const int x0 = (int)x0f;
        const int y0 = (int)y0f;
        const int x1 = min(x0 + 1, WW - 1);
        const int y1 = min(y0 + 1, HH - 1);
        const float* r0 = xb + (size_t)(y0 * WW) * CC + c;
        const float* r1 = xb + (size_t)(y1 * WW) * CC + c;
        const float v00 = r0[(size_t)x0 * CC];
        const float v01 = r0[(size_t)x1 * CC];
        const float v10 = r1[(size_t)x0 * CC];
        const float v11 = r1[(size_t)x1 * CC];
        ob[c] = v00 * (1.f - wx) * (1.f - wy) + v01 * wx * (1.f - wy)
              + v10 * (1.f - wx) * wy + v11 * wx * wy;
    }
}

extern "C" void kernel_launch(void* const* d_in, const int* in_sizes, int n_in,
                              void* d_out, int out_size, void* d_ws, size_t ws_size,
                              hipStream_t stream) {
    const float* x     = (const float*)d_in[0];
    const float* dw_w  = (const float*)d_in[1];
    const float* dw_b  = (const float*)d_in[2];
    const float* off_w = (const float*)d_in[3];
    const float* off_b = (const float*)d_in[4];
    const float* wt_w  = (const float*)d_in[5];
    const float* wt_b  = (const float*)d_in[6];

    float* ixiy = (float*)d_ws;                             // 1 MiB
    float* offpart = (float*)d_ws + 2 * BB * GG * NN;       // 6.29 MiB
    const size_t need = (size_t)(2 * BB * GG * NN + BB * NN * 48) * 4;

    if (ws_size >= need) {
        dq_conv_offpart<<<BB * HH * NCHUNK, CHUNK, 0, stream>>>(
            x, dw_w, dw_b, off_w, offpart);
        dq_coords<<<BB * NN / 4, 256, 0, stream>>>(
            x, offpart, off_b, wt_w, wt_b, ixiy);
    } else {
        dqshift_offsets_kernel<<<BB * NN / 4, 256, 0, stream>>>(
            x, dw_w, dw_b, off_w, off_b, wt_w, wt_b, ixiy);
    }
    dqshift_sample_kernel<<<BB * NN, 256, 0, stream>>>(x, ixiy, (float*)d_out);
}

// Round 4
// 111.743 us; speedup vs baseline: 2.3799x; 1.3215x over previous
//
#include <hip/hip_runtime.h>
#include <math.h>

// Problem constants: B=8, N=4096, C=768, H=W=64, GROUPS=4.
#define BB 8
#define CC 768
#define HH 64
#define WW 64
#define NN 4096
#define GG 4
#define NCHUNK 6
#define CHUNK 128   /* channels per A1 block */

typedef __attribute__((ext_vector_type(8))) short short8;
typedef __attribute__((ext_vector_type(4))) float f32x4;

__device__ __forceinline__ float gelu_exact(float v) {
    return 0.5f * v * (1.0f + erff(v * 0.70710678118654752f));
}

__device__ __forceinline__ unsigned short f2bf(float f) {   // RNE float->bf16
    union { float f; unsigned u; } v; v.f = f;
    unsigned r = v.u + 0x7FFFu + ((v.u >> 16) & 1u);
    return (unsigned short)(r >> 16);
}

// ---------------------------------------------------------------------------
// A1: block = (b, h, chunk of 128 ch), 128 threads (2 waves).
// Phase 1 (per 32-col half): sliding 3x3 depthwise conv (batch-8 register
// prefetch), exact GELU; stage gelu AND center-x as bf16 in LDS.
// Phase 2 (MFMA): D[pos][n] = [gelu|xc](pos,256k) x blockdiag(off_w, wt_w):
// one f32x4 accumulator, 8 x mfma_f32_16x16x32_bf16 per wave per half.
// Cols n<8 = off partials, n>=8 = wt partials -> offpart[chunk][n][gpos].
// ---------------------------------------------------------------------------
__global__ __launch_bounds__(128, 4) void dq_conv_mfma(
    const float* __restrict__ x,      // (B, N, C)
    const float* __restrict__ dw_w,   // (C, 9)
    const float* __restrict__ dw_b,   // (C,)
    const float* __restrict__ off_w,  // (8, C)
    const float* __restrict__ wt_w,   // (8, C)
    float* __restrict__ offpart)      // (NCHUNK, 16, B*N)
{
    __shared__ unsigned short gl[32][136];   // gelu, bf16, half-row
    __shared__ unsigned short xh[32][136];   // center x, bf16, half-row
    const int t = threadIdx.x;
    const int lane = t & 63, wv = t >> 6;
    int bid = blockIdx.x;
    const int chunk = bid % NCHUNK; bid /= NCHUNK;
    const int h = bid % HH;
    const int b = bid / HH;
    const int c = chunk * CHUNK + t;

    // ---- B fragments: blockdiag [off_w ; wt_w], built once, kept in regs ----
    const int n = lane & 15, kg = lane >> 4;
    short8 bfrag[8];
#pragma unroll
    for (int kt = 0; kt < 8; ++kt) {
        const bool isOff = (kt < 4);
        const bool valid = isOff ? (n < 8) : (n >= 8);
        const int krow = isOff ? kt : kt - 4;
        const float* wp = isOff ? (off_w + (n < 8 ? n : 0) * CC)
                                : (wt_w + (n >= 8 ? n - 8 : 0) * CC);
        const float* src = wp + chunk * CHUNK + krow * 32 + kg * 8;
        short8 bf;
#pragma unroll
        for (int j = 0; j < 8; ++j) {
            const float v = valid ? src[j] : 0.f;
            bf[j] = (short)f2bf(v);
        }
        bfrag[kt] = bf;
    }

    float w9[9];
#pragma unroll
    for (int j = 0; j < 9; ++j) w9[j] = dw_w[c * 9 + j];
    const float bias = dw_b[c];

    const float* rowc = x + (size_t)(b * NN + h * WW) * CC + c;
    const bool hm = (h > 0), hp = (h < HH - 1);
    const int RS = WW * CC;

    float cur0[8], cur1[8], cur2[8], nxt0[8], nxt1[8], nxt2[8];
    float pl0 = 0.f, pl1 = 0.f, pl2 = 0.f;

#pragma unroll
    for (int j = 0; j < 8; ++j) {
        const float* p = rowc + (size_t)j * CC;
        cur1[j] = p[0];
        cur0[j] = hm ? p[-RS] : 0.f;
        cur2[j] = hp ? p[RS] : 0.f;
    }

    for (int wb = 0; wb < 8; ++wb) {
        if (wb < 7) {
#pragma unroll
            for (int j = 0; j < 8; ++j) {
                const float* p = rowc + (size_t)(wb * 8 + 8 + j) * CC;
                nxt1[j] = p[0];
                nxt0[j] = hm ? p[-RS] : 0.f;
                nxt2[j] = hp ? p[RS] : 0.f;
            }
        } else {
#pragma unroll
            for (int j = 0; j < 8; ++j) { nxt0[j] = 0.f; nxt1[j] = 0.f; nxt2[j] = 0.f; }
        }
#pragma unroll
        for (int j = 0; j < 8; ++j) {
            const float l0 = j ? cur0[j - 1] : pl0;
            const float l1 = j ? cur1[j - 1] : pl1;
            const float l2 = j ? cur2[j - 1] : pl2;
            const float r0 = (j == 7) ? nxt0[0] : cur0[j + 1];
            const float r1 = (j == 7) ? nxt1[0] : cur1[j + 1];
            const float r2 = (j == 7) ? nxt2[0] : cur2[j + 1];
            float conv = l0 * w9[0] + cur0[j] * w9[1] + r0 * w9[2]
                       + l1 * w9[3] + cur1[j] * w9[4] + r1 * w9[5]
                       + l2 * w9[6] + cur2[j] * w9[7] + r2 * w9[8];
            const int wl = (wb & 3) * 8 + j;     // row within half
            gl[wl][t] = f2bf(gelu_exact(conv + bias));
            xh[wl][t] = f2bf(cur1[j]);
        }
        pl0 = cur0[7]; pl1 = cur1[7]; pl2 = cur2[7];
#pragma unroll
        for (int j = 0; j < 8; ++j) { cur0[j] = nxt0[j]; cur1[j] = nxt1[j]; cur2[j] = nxt2[j]; }

        if (wb == 3 || wb == 7) {
            const int half = wb >> 2;
            __syncthreads();
            // ---- MFMA phase: wave wv covers positions wv*16..wv*16+15 of this half
            f32x4 acc = {0.f, 0.f, 0.f, 0.f};
            const int arow = wv * 16 + n;
#pragma unroll
            for (int kt = 0; kt < 4; ++kt) {
                const short8 a = *(const short8*)&gl[arow][kt * 32 + kg * 8];
                acc = __builtin_amdgcn_mfma_f32_16x16x32_bf16(a, bfrag[kt], acc, 0, 0, 0);
            }
#pragma unroll
            for (int kt = 0; kt < 4; ++kt) {
                const short8 a = *(const short8*)&xh[arow][kt * 32 + kg * 8];
                acc = __builtin_amdgcn_mfma_f32_16x16x32_bf16(a, bfrag[4 + kt], acc, 0, 0, 0);
            }
            // D: col = n = lane&15, rows kg*4..kg*4+3 (contiguous positions)
            const int posl = half * 32 + wv * 16 + kg * 4;
            const size_t gpos = (size_t)(b * NN + h * WW) + posl;
            float4 st; st.x = acc[0]; st.y = acc[1]; st.z = acc[2]; st.w = acc[3];
            *(float4*)&offpart[((size_t)(chunk * 16 + n)) * (BB * NN) + gpos] = st;
            if (wb == 3) __syncthreads();
        }
    }
}

// ---------------------------------------------------------------------------
// Combine: sum 6 chunk partials for off & wt, sigmoid gate, shift, clip.
// thread: o = t>>5 (0..7), pos = blk*32 + (t&31).
// ---------------------------------------------------------------------------
__global__ __launch_bounds__(256) void dq_combine(
    const float* __restrict__ offpart,  // (NCHUNK, 16, B*N)
    const float* __restrict__ off_b,
    const float* __restrict__ wt_b,
    float* __restrict__ ixiy)           // (2, B*G, N)
{
    const int t = threadIdx.x;
    const int o = t >> 5;
    const int gpos = blockIdx.x * 32 + (t & 31);
    const int b = gpos >> 12;
    const int hw = gpos & 4095;
    const int h = hw >> 6, w = hw & 63;

    float so = 0.f, sw = 0.f;
#pragma unroll
    for (int ch = 0; ch < NCHUNK; ++ch) {
        so += offpart[((size_t)(ch * 16 + o)) * (BB * NN) + gpos];
        sw += offpart[((size_t)(ch * 16 + 8 + o)) * (BB * NN) + gpos];
    }
    const float sig = 1.f / (1.f + expf(-(sw + wt_b[o])));
    const float val = (so + off_b[o]) * sig;

    if (o < 4) {
        const float shx = (o == 2) ? -1.f : ((o == 3) ? 1.f : 0.f);
        const float ix = fminf(fmaxf((float)w + val + shx, 0.f), (float)(WW - 1));
        ixiy[(b * GG + o) * NN + hw] = ix;
    } else {
        const int g = o - 4;
        const float shy = (g == 0) ? -1.f : ((g == 1) ? 1.f : 0.f);
        const float iy = fminf(fmaxf((float)h + val + shy, 0.f), (float)(HH - 1));
        ixiy[BB * GG * NN + (b * GG + g) * NN + hw] = iy;
    }
}

// ---------------------------------------------------------------------------
// Fallback (1 MiB ws): round-1 fused offsets kernel.
// ---------------------------------------------------------------------------
__global__ __launch_bounds__(256) void dqshift_offsets_kernel(
    const float* __restrict__ x, const float* __restrict__ dw_w,
    const float* __restrict__ dw_b, const float* __restrict__ off_w,
    const float* __restrict__ off_b, const float* __restrict__ wt_w,
    const float* __restrict__ wt_b, float* __restrict__ ixiy)
{
    const int wave = threadIdx.x >> 6;
    const int lane = threadIdx.x & 63;
    const int p = blockIdx.x * 4 + wave;
    const int b = p >> 12;
    const int hw = p & 4095;
    const int h = hw >> 6;
    const int w = hw & 63;
    const float* xb = x + (size_t)b * NN * CC;
    float accO[8], accW[8];
#pragma unroll
    for (int o = 0; o < 8; ++o) { accO[o] = 0.f; accW[o] = 0.f; }
    for (int k = 0; k < CC / 64; ++k) {
        const int c = lane + (k << 6);
        float conv = 0.f, xc = 0.f;
#pragma unroll
        for (int dy = -1; dy <= 1; ++dy) {
            const int hh = h + dy;
            const bool vy = (hh >= 0) && (hh < HH);
#pragma unroll
            for (int dx = -1; dx <= 1; ++dx) {
                const int ww = w + dx;
                const bool vv = vy && (ww >= 0) && (ww < WW);
                const float tt = vv ? xb[(size_t)(hh * WW + ww) * CC + c] : 0.f;
                if (dy == 0 && dx == 0) xc = tt;
                conv = fmaf(tt, dw_w[c * 9 + (dy + 1) * 3 + (dx + 1)], conv);
            }
        }
        const float gv = conv + dw_b[c];
        const float gle = 0.5f * gv * (1.0f + erff(gv * 0.70710678118654752f));
#pragma unroll
        for (int o = 0; o < 8; ++o) {
            accO[o] = fmaf(gle, off_w[o * CC + c], accO[o]);
            accW[o] = fmaf(xc, wt_w[o * CC + c], accW[o]);
        }
    }
#pragma unroll
    for (int o = 0; o < 8; ++o) {
#pragma unroll
        for (int s = 32; s > 0; s >>= 1) {
            accO[o] += __shfl_xor(accO[o], s, 64);
            accW[o] += __shfl_xor(accW[o], s, 64);
        }
    }
    if (lane == 0) {
        const float shx[4] = {0.f, 0.f, -1.f, 1.f};
        const float shy[4] = {-1.f, 1.f, 0.f, 0.f};
#pragma unroll
        for (int g = 0; g < 4; ++g) {
            const float sx = 1.f / (1.f + expf(-(accW[g] + wt_b[g])));
            const float sy = 1.f / (1.f + expf(-(accW[4 + g] + wt_b[4 + g])));
            const float ox = (accO[g] + off_b[g]) * sx + shx[g];
            const float oy = (accO[4 + g] + off_b[4 + g]) * sy + shy[g];
            const float ix = fminf(fmaxf((float)w + ox, 0.f), (float)(WW - 1));
            const float iy = fminf(fmaxf((float)h + oy, 0.f), (float)(HH - 1));
            const int idx = (b * GG + g) * NN + hw;
            ixiy[idx] = ix;
            ixiy[BB * GG * NN + idx] = iy;
        }
    }
}

// ---------------------------------------------------------------------------
// B: bilinear border sampling, one block per position, channel-coalesced.
// ---------------------------------------------------------------------------
__global__ __launch_bounds__(256) void dqshift_sample_kernel(
    const float* __restrict__ x,
    const float* __restrict__ ixiy,
    float* __restrict__ out)
{
    const int p = blockIdx.x;
    const int b = p >> 12;
    const int hw = p & 4095;
    const float* xb = x + (size_t)b * NN * CC;
    float* ob = out + (size_t)p * CC;

#pragma unroll
    for (int k = 0; k < 3; ++k) {
        const int c = threadIdx.x + (k << 8);
        const int g = c / (CC / GG);
        const int idx = (b * GG + g) * NN + hw;
        const float ix = ixiy[idx];
        const float iy = ixiy[BB * GG * NN + idx];
        const float x0f = floorf(ix);
        const float y0f = floorf(iy);
        const float wx = ix - x0f;
        const float wy = iy - y0f;
        const int x0 = (int)x0f;
        const int y0 = (int)y0f;
        const int x1 = min(x0 + 1, WW - 1);
        const int y1 = min(y0 + 1, HH - 1);
        const float* r0 = xb + (size_t)(y0 * WW) * CC + c;
        const float* r1 = xb + (size_t)(y1 * WW) * CC + c;
        const float v00 = r0[(size_t)x0 * CC];
        const float v01 = r0[(size_t)x1 * CC];
        const float v10 = r1[(size_t)x0 * CC];
        const float v11 = r1[(size_t)x1 * CC];
        ob[c] = v00 * (1.f - wx) * (1.f - wy) + v01 * wx * (1.f - wy)
              + v10 * (1.f - wx) * wy + v11 * wx * wy;
    }
}

extern "C" void kernel_launch(void* const* d_in, const int* in_sizes, int n_in,
                              void* d_out, int out_size, void* d_ws, size_t ws_size,
                              hipStream_t stream) {
    const float* x     = (const float*)d_in[0];
    const float* dw_w  = (const float*)d_in[1];
    const float* dw_b  = (const float*)d_in[2];
    const float* off_w = (const float*)d_in[3];
    const float* off_b = (const float*)d_in[4];
    const float* wt_w  = (const float*)d_in[5];
    const float* wt_b  = (const float*)d_in[6];

    float* ixiy = (float*)d_ws;                              // 1 MiB
    float* offpart = (float*)d_ws + 2 * BB * GG * NN;        // 12.58 MiB
    const size_t need = (size_t)(2 * BB * GG * NN + NCHUNK * 16 * BB * NN) * 4;

    if (ws_size >= need) {
        dq_conv_mfma<<<BB * HH * NCHUNK, 128, 0, stream>>>(
            x, dw_w, dw_b, off_w, wt_w, offpart);
        dq_combine<<<BB * NN / 32, 256, 0, stream>>>(
            offpart, off_b, wt_b, ixiy);
    } else {
        dqshift_offsets_kernel<<<BB * NN / 4, 256, 0, stream>>>(
            x, dw_w, dw_b, off_w, off_b, wt_w, wt_b, ixiy);
    }
    dqshift_sample_kernel<<<BB * NN, 256, 0, stream>>>(x, ixiy, (float*)d_out);
}